// Round 8
// baseline (239.187 us; speedup 1.0000x reference)
//
#include <hip/hip_runtime.h>

// TriangleLinear: out[b][8191-r] = bias[r] + sum_{c>=max(0,r-4)} W_packed[...] * x[b][c]
// HBM floor: 134.4 MB packed-weight stream read once => ~21 us kernel.
//
// Measurement model: dur_us ~= kernel + ~156 us harness re-poison fills (rocprof
// top-5 shows only 77-80us fillBufferAligned; our kernel dispatch < 77us).
//   R0 scalar w + nt:                 ~41 us (197)
//   R2 strided, no-nt:                ~52 us (208)
//   R3 scalar + manual dbuf, no-nt:   ~51 us (207)  (dbuf: VGPR spill poison)
//   R5 dwordx4 + nt + manual dbuf:    ~54 us (210)
//   R6 dwordx4 + nt, simple loop:     ~41 us (197)  == R0 (instr count irrelevant)
//   R7 shfl epilogue + bounds(,5):    ~55 us (212)  (192 ds_swizzle/thread ~13us
//                                                    + VGPR-102 squeeze)
// Per-tile period = 41us*2.4GHz/36 tiles ~= 2730 cyc >> 1250 model: the compiler's
// per-iteration vmcnt(0) serializes {issue, full nt-HBM latency, FMA} each 1024
// cols; 4 waves/SIMD can't cover the stalls. The latency tax is per-ITERATION.
//
// R8: amortize it. VEC 4->8 (TILE=2048): 2x dwordx4 w per row per iter, half the
// iterations, double the FMA per stall. x processed PER-BATCH inside the tile
// (8 transient regs, not 64) to stay ~100 VGPR (R3/R5 lesson: stay under 128).
// Same column-ascending summation order => absmax must stay 0.0625.
// Epilogue = R6's 35 KB LDS reduction (R7's shfl storm reverted).

constexpr int N = 8192;      // N_IN == N_OUT
constexpr int BATCH = 8;
constexpr int ROWS = 4;      // rows per block: x loads shared across rows
constexpr int THREADS = 256;
constexpr int VEC = 8;       // columns per thread (2 x dwordx4 w per row)
constexpr int TILE = THREADS * VEC;  // 2048 columns per block-iteration

typedef float f32x4 __attribute__((ext_vector_type(4)));

__global__ __launch_bounds__(THREADS, 4)
void tri_linear_kernel(const float* __restrict__ x,
                       const float* __restrict__ w,
                       const float* __restrict__ bias,
                       float* __restrict__ out) {
  const int t = threadIdx.x;
  const int r0 = blockIdx.x * ROWS;

  // Per-row triangular start column and packed-row base pointers (uniform -> SGPR).
  int c0[ROWS];
  const float* wrow[ROWS];
#pragma unroll
  for (int i = 0; i < ROWS; ++i) {
    const int r = r0 + i;
    c0[i] = (r > 4) ? (r - 4) : 0;
    // off(r) = 8192*r - (r-5)(r-4)/2 for r>=5, else 8192*r. (off(8192)=33,591,286 = nW)
    long long off = (r <= 5)
        ? (long long)r * N
        : (long long)r * N - ((long long)(r - 5) * (long long)(r - 4)) / 2;
    wrow[i] = w + (off - (long long)c0[i]);   // wrow[i][c] valid for c in [c0[i], N)
  }
  const int cbA = c0[0] & ~(TILE - 1);        // c0[0] == min c0 of this block's rows
  // c0[0] = r0-4 is a multiple of 4 => c0[0] <= cbA+TILE-4 => c0[i] <= cbA+TILE-1:
  // every row's triangular start falls inside the edge tile; main loop predicate-free.

  float acc[ROWS][BATCH];
#pragma unroll
  for (int i = 0; i < ROWS; ++i)
#pragma unroll
    for (int b = 0; b < BATCH; ++b) acc[i][b] = 0.0f;

  const int cT = VEC * t;   // this thread's packed column offset within a tile

  // ---- Edge tile [cbA, cbA+TILE): predicated on the triangular boundary ----
  {
    const int c = cbA + cT;
    float wvE[ROWS][VEC];                     // 32 regs, predicated scalar nt loads
#pragma unroll
    for (int i = 0; i < ROWS; ++i)
#pragma unroll
      for (int j = 0; j < VEC; ++j) {
        const int cj = c + j;
        wvE[i][j] = (cj >= c0[i]) ? __builtin_nontemporal_load(wrow[i] + cj) : 0.0f;
      }
#pragma unroll
    for (int b = 0; b < BATCH; ++b) {
      const float4 xa = *(const float4*)(x + b * N + c);
      const float4 xb = *(const float4*)(x + b * N + c + 4);
      const float* xae = reinterpret_cast<const float*>(&xa);
      const float* xbe = reinterpret_cast<const float*>(&xb);
#pragma unroll
      for (int i = 0; i < ROWS; ++i) {
#pragma unroll
        for (int j = 0; j < 4; ++j)
          acc[i][b] = fmaf(wvE[i][j], xae[j], acc[i][b]);
#pragma unroll
        for (int j = 0; j < 4; ++j)
          acc[i][b] = fmaf(wvE[i][4 + j], xbe[j], acc[i][b]);
      }
    }
  }

  // ---- Main loop: predicate-free; 8 nt dwordx4 w loads; x per-batch (low VGPR) ----
  for (int cb = cbA + TILE; cb < N; cb += TILE) {
    const int c = cb + cT;
    f32x4 wv[ROWS][2];
#pragma unroll
    for (int i = 0; i < ROWS; ++i) {
      wv[i][0] = __builtin_nontemporal_load(
          reinterpret_cast<const f32x4*>(wrow[i] + c));       // 4B-aligned x4 OK
      wv[i][1] = __builtin_nontemporal_load(
          reinterpret_cast<const f32x4*>(wrow[i] + c + 4));   // (R5-verified)
    }
#pragma unroll
    for (int b = 0; b < BATCH; ++b) {
      const float4 xa = *(const float4*)(x + b * N + c);      // L2-hot
      const float4 xb = *(const float4*)(x + b * N + c + 4);
      const float* xae = reinterpret_cast<const float*>(&xa);
      const float* xbe = reinterpret_cast<const float*>(&xb);
#pragma unroll
      for (int i = 0; i < ROWS; ++i) {
#pragma unroll
        for (int j = 0; j < 4; ++j)
          acc[i][b] = fmaf(wv[i][0][j], xae[j], acc[i][b]);
#pragma unroll
        for (int j = 0; j < 4; ++j)
          acc[i][b] = fmaf(wv[i][1][j], xbe[j], acc[i][b]);
      }
    }
  }

  // ---- Reduction: 32 (row,batch) sums over 256 threads, transposed LDS tile ----
  // red[256][33] = 33.8 KB (4 blocks/CU). Pad 33 -> write bank (t + s) % 32 (2-way,
  // free) and read bank (k + s) % 32 with s spanning 0..31 across the wave (2-way, free).
  __shared__ float red[THREADS][ROWS * BATCH + 1];
#pragma unroll
  for (int i = 0; i < ROWS; ++i)
#pragma unroll
    for (int b = 0; b < BATCH; ++b)
      red[t][i * BATCH + b] = acc[i][b];
  __syncthreads();

  const int s = t & 31;     // which (row,batch) sum
  const int part = t >> 5;  // which 32-thread chunk
  float p = 0.0f;
#pragma unroll
  for (int k = 0; k < 32; ++k) p += red[part * 32 + k][s];

  __shared__ float red2[32][9];
  red2[s][part] = p;
  __syncthreads();

  if (t < 32) {
    float total = 0.0f;
#pragma unroll
    for (int g = 0; g < 8; ++g) total += red2[t][g];
    const int i = t >> 3, b = t & 7;   // t == i*BATCH + b == s
    const int r = r0 + i;
    out[b * N + (N - 1 - r)] = total + bias[r];  // last-dim flip + bias
  }
}

extern "C" void kernel_launch(void* const* d_in, const int* in_sizes, int n_in,
                              void* d_out, int out_size, void* d_ws, size_t ws_size,
                              hipStream_t stream) {
  const float* x    = (const float*)d_in[0];  // [8, 8192]
  const float* w    = (const float*)d_in[1];  // [33591286] packed triangular
  const float* bias = (const float*)d_in[2];  // [8192]
  float* out = (float*)d_out;                 // [8, 8192]
  tri_linear_kernel<<<N / ROWS, THREADS, 0, stream>>>(x, w, bias, out);
}

// Round 9
// 210.745 us; speedup vs baseline: 1.1350x; 1.1350x over previous
//
#include <hip/hip_runtime.h>

// TriangleLinear: out[b][8191-r] = bias[r] + sum_{c>=max(0,r-4)} W_packed[...] * x[b][c]
// HBM floor: 134.4 MB packed-weight stream read once => ~21 us kernel.
//
// Ledger (kernel us ~= dur_us - 156 us harness fills; R8 finally exposed counters):
//   R0/R6 (scalar|dwordx4 w + nt):  ~41 us (197)  best; instr count irrelevant
//   R2 no-nt:                       ~52 us  w allocating in L2 evicts hot x
//   R3/R5 manual dbuf:              ~51-54  VGPR pressure/spills kill MLP
//   R7 shfl-storm epilogue:         ~55     192 ds_swizzle/thread ~13us
//   R8 VEC=8, per-batch x:          ~84-86  compiler squeezed to 64 VGPR ->
//                                           serialized loads + 21MB scratch writes
// R8 counters: FETCH 121 MB (= w read ONCE, no over-fetch), VALUBusy 10%,
// Occupancy 38%, conflicts 0 => pure latency-bound, starved of waves. 16 waves/CU
// (35 KB LDS cap + ~100 VGPR) can't cover ~900-2000cyc nt-HBM stalls; the 6.3+
// TB/s copy/fill kernels run ~32 waves/CU.
//
// R9: ROWS 4->2 (grid 4096), SAME R6 load/FMA structure. Per-thread state:
// acc 16 + xv 32 + wv 8 + addr ~= 66-75 VGPR -> 6-7 waves/SIMD; epilogue is 16
// sums -> 18.5 KB LDS -> 6-7 blocks/CU. Net 24-28 waves/CU (+50-75% latency
// hiding). launch_bounds(256,6) caps VGPR at 85 (spill-safe guardrail).
// Predict: kernel ~25-30us => dur_us ~181-186, Occupancy ~75%.

constexpr int N = 8192;      // N_IN == N_OUT
constexpr int BATCH = 8;
constexpr int ROWS = 2;      // rows per block (halved: more blocks, more waves/CU)
constexpr int THREADS = 256;
constexpr int VEC = 4;       // columns per thread (packed: float4 x, dwordx4 w)
constexpr int TILE = THREADS * VEC;  // 1024 columns per block-iteration

typedef float f32x4 __attribute__((ext_vector_type(4)));

__global__ __launch_bounds__(THREADS, 6)
void tri_linear_kernel(const float* __restrict__ x,
                       const float* __restrict__ w,
                       const float* __restrict__ bias,
                       float* __restrict__ out) {
  const int t = threadIdx.x;
  const int r0 = blockIdx.x * ROWS;

  // Per-row triangular start column and packed-row base pointers (uniform -> SGPR).
  int c0[ROWS];
  const float* wrow[ROWS];
#pragma unroll
  for (int i = 0; i < ROWS; ++i) {
    const int r = r0 + i;
    c0[i] = (r > 4) ? (r - 4) : 0;
    // off(r) = 8192*r - (r-5)(r-4)/2 for r>=5, else 8192*r. (off(8192)=33,591,286 = nW)
    long long off = (r <= 5)
        ? (long long)r * N
        : (long long)r * N - ((long long)(r - 5) * (long long)(r - 4)) / 2;
    wrow[i] = w + (off - (long long)c0[i]);   // wrow[i][c] valid for c in [c0[i], N)
  }
  const int cbA = c0[0] & ~(TILE - 1);        // c0[0] == min c0 of this block's rows
  // c0[0] = r0-4 (r0 even) is even => c0[0] <= cbA+1022 => c0[1] <= cbA+1023:
  // both rows' triangular starts fall inside the edge tile; main loop predicate-free.

  float acc[ROWS][BATCH];
#pragma unroll
  for (int i = 0; i < ROWS; ++i)
#pragma unroll
    for (int b = 0; b < BATCH; ++b) acc[i][b] = 0.0f;

  const int c4 = VEC * t;   // this thread's packed column offset within a tile

  // ---- Edge tile [cbA, cbA+TILE): predicated on the triangular boundary ----
  {
    const int c = cbA + c4;
    float4 xv[BATCH];
#pragma unroll
    for (int b = 0; b < BATCH; ++b)
      xv[b] = *(const float4*)(x + b * N + c);
#pragma unroll
    for (int i = 0; i < ROWS; ++i) {
#pragma unroll
      for (int j = 0; j < VEC; ++j) {
        const int cj = c + j;
        const float wv = (cj >= c0[i]) ? __builtin_nontemporal_load(wrow[i] + cj)
                                       : 0.0f;
        const float* xe;
#pragma unroll
        for (int b = 0; b < BATCH; ++b) {
          xe = reinterpret_cast<const float*>(&xv[b]);
          acc[i][b] = fmaf(wv, xe[j], acc[i][b]);
        }
      }
    }
  }

  // ---- Main loop: R6 structure verbatim (keep per-wave MLP; no manual dbuf) ----
  for (int cb = cbA + TILE; cb < N; cb += TILE) {
    const int c = cb + c4;
    float4 xv[BATCH];
#pragma unroll
    for (int b = 0; b < BATCH; ++b)
      xv[b] = *(const float4*)(x + b * N + c);   // L2-hot
    f32x4 wv4[ROWS];
#pragma unroll
    for (int i = 0; i < ROWS; ++i)
      wv4[i] = __builtin_nontemporal_load(
          reinterpret_cast<const f32x4*>(wrow[i] + c));  // 4B-aligned x4: OK
                                                         // (R5-verified)
#pragma unroll
    for (int i = 0; i < ROWS; ++i)
#pragma unroll
      for (int j = 0; j < VEC; ++j) {
        const float* xe;
#pragma unroll
        for (int b = 0; b < BATCH; ++b) {
          xe = reinterpret_cast<const float*>(&xv[b]);
          acc[i][b] = fmaf(wv4[i][j], xe[j], acc[i][b]);
        }
      }
  }

  // ---- Reduction: 16 (row,batch) sums over 256 threads, 18.5 KB LDS ----
  // red[256][17]: stride 17 (odd) => writes/reads land <=2 lanes/bank (free).
  __shared__ float red[THREADS][ROWS * BATCH + 1];
  __shared__ float red2[16][17];
#pragma unroll
  for (int i = 0; i < ROWS; ++i)
#pragma unroll
    for (int b = 0; b < BATCH; ++b)
      red[t][i * BATCH + b] = acc[i][b];
  __syncthreads();

  {
    const int u = t & 15;   // which (row,batch) sum
    const int p = t >> 4;   // which 16-thread chunk (16 parts)
    float s = 0.0f;
#pragma unroll
    for (int k = 0; k < 16; ++k) s += red[p * 16 + k][u];
    red2[u][p] = s;
  }
  __syncthreads();

  if (t < ROWS * BATCH) {
    float total = 0.0f;
#pragma unroll
    for (int g = 0; g < 16; ++g) total += red2[t][g];
    const int i = t >> 3, b = t & 7;   // t == i*BATCH + b
    const int r = r0 + i;
    out[b * N + (N - 1 - r)] = total + bias[r];  // last-dim flip + bias
  }
}

extern "C" void kernel_launch(void* const* d_in, const int* in_sizes, int n_in,
                              void* d_out, int out_size, void* d_ws, size_t ws_size,
                              hipStream_t stream) {
  const float* x    = (const float*)d_in[0];  // [8, 8192]
  const float* w    = (const float*)d_in[1];  // [33591286] packed triangular
  const float* bias = (const float*)d_in[2];  // [8192]
  float* out = (float*)d_out;                 // [8, 8192]
  tri_linear_kernel<<<N / ROWS, THREADS, 0, stream>>>(x, w, bias, out);
}

// Round 10
// 202.477 us; speedup vs baseline: 1.1813x; 1.0408x over previous
//
#include <hip/hip_runtime.h>
#include <stdint.h>

// TriangleLinear: out[b][8191-r] = bias[r] + sum_{c>=max(0,r-4)} W_packed[...] * x[b][c]
// HBM floor: 134.4 MB packed-weight stream read once => ~21 us kernel.
//
// Ledger (kernel us ~= dur_us - 156 us harness fills):
//   R0/R6 best:      ~41 us (197)   all 6 perturbations below regressed:
//   R2 no-nt+strided ~52 | R3 reg-dbuf ~51 | R5 dwordx4+dbuf ~54 | R7 shfl ~55
//   R8 VEC8/64VGPR   ~84 (counters: FETCH=121MB w-read-ONCE, VALUBusy 10%,
//                        occupancy 38%, conflicts 0 -> pure latency-bound)
//   R9 ROWS=2 occup. ~54 (occupancy refuted; fills hit 86% peak at 9.7% occ)
// R6 per-wave iteration period ~11K cyc >> 1.3K model: each wave serializes
// {issue 12KB loads -> vmcnt drain -> FMA}; compiler can't pipeline across
// iterations (in-order vmcnt, no spare regs) and wave-overlap isn't happening.
//
// R10: async DMA staging — the one structural tool untried, ZERO VGPR cost
// (dodges R3/R5's register trap). Double-buffered w tiles in LDS via
// global_load_lds (T3-minimal 2-phase, guide §5):
//   per tile: {x loads (issued FIRST) -> DMA next tile (16x dword, async,
//   no dest regs) -> ds_read_b128 + 128 FMA -> syncthreads (vmcnt0: DMA had
//   the whole compute phase to fly)}.
// Reduction LDS aliased over w buffers: max(32.0, 34.9) KB -> 4 blocks/CU kept.
// Predict: kernel ~25 us => dur_us ~181; absmax stays 0.0625 (same FMA order).

constexpr int N = 8192;      // N_IN == N_OUT
constexpr int BATCH = 8;
constexpr int ROWS = 4;      // rows per block
constexpr int THREADS = 256;
constexpr int VEC = 4;       // columns per thread
constexpr int TILE = THREADS * VEC;  // 1024 columns per block-iteration

typedef float f32x4 __attribute__((ext_vector_type(4)));

__device__ __forceinline__ void stage_dword(const float* gsrc, float* ldst_uniform) {
  // Async global->LDS DMA: 64 lanes x 4B. LDS dest is wave-uniform base +
  // lane*4 (HW rule); gsrc is per-lane. Increments vmcnt; no VGPR dest.
  __builtin_amdgcn_global_load_lds(
      (__attribute__((address_space(1))) void*)gsrc,
      (__attribute__((address_space(3))) void*)ldst_uniform, 4, 0, 0);
}

__global__ __launch_bounds__(THREADS, 4)
void tri_linear_kernel(const float* __restrict__ x,
                       const float* __restrict__ w,
                       const float* __restrict__ bias,
                       float* __restrict__ out) {
  const int t = threadIdx.x;
  const int r0 = blockIdx.x * ROWS;

  // smem layout: [0, 8192) = two w tile buffers [2][ROWS][1024];
  // after the main loop the same memory is reused for the reduction.
  __shared__ float smem[8736];   // 34,944 B -> 4 blocks/CU (160 KB budget)

  // Per-row triangular start column and packed-row base pointers (uniform -> SGPR).
  int c0[ROWS];
  const float* wrow[ROWS];
#pragma unroll
  for (int i = 0; i < ROWS; ++i) {
    const int r = r0 + i;
    c0[i] = (r > 4) ? (r - 4) : 0;
    // off(r) = 8192*r - (r-5)(r-4)/2 for r>=5, else 8192*r. (off(8192)=33,591,286 = nW)
    long long off = (r <= 5)
        ? (long long)r * N
        : (long long)r * N - ((long long)(r - 5) * (long long)(r - 4)) / 2;
    wrow[i] = w + (off - (long long)c0[i]);   // wrow[i][c] valid for c in [c0[i], N)
  }
  const int cbA = c0[0] & ~(TILE - 1);        // c0[0] == min c0 of this block's rows
  // c0[0] = r0-4 is a multiple of 4 => all rows' triangular starts fall inside the
  // edge tile; main-loop tiles are predicate-free and fully in-bounds.

  // This wave stages row `wv` of each tile (recomputed pointer: no dynamic
  // indexing into wrow[] -> no scratch, rule #20).
  const int wv = t >> 6, lane = t & 63;
  const int rv = r0 + wv;
  const int c0v = (rv > 4) ? (rv - 4) : 0;
  const long long offv = (rv <= 5)
      ? (long long)rv * N
      : (long long)rv * N - ((long long)(rv - 5) * (long long)(rv - 4)) / 2;
  const float* wsrc = w + (offv - (long long)c0v);  // wsrc[c] valid on main tiles

  float acc[ROWS][BATCH];
#pragma unroll
  for (int i = 0; i < ROWS; ++i)
#pragma unroll
    for (int b = 0; b < BATCH; ++b) acc[i][b] = 0.0f;

  const int c4 = VEC * t;   // this thread's packed column offset within a tile

  // ---- Prologue: kick off DMA of the first main tile into buf0 ----
  if (cbA + TILE < N) {
#pragma unroll
    for (int k = 0; k < 16; ++k)
      stage_dword(wsrc + (cbA + TILE) + k * 64 + lane,
                  &smem[wv * 1024 + k * 64]);
  }

  // ---- Edge tile [cbA, cbA+TILE): predicated register path (overlaps DMA) ----
  {
    const int c = cbA + c4;
    float4 xv[BATCH];
#pragma unroll
    for (int b = 0; b < BATCH; ++b)
      xv[b] = *(const float4*)(x + b * N + c);
#pragma unroll
    for (int i = 0; i < ROWS; ++i) {
#pragma unroll
      for (int j = 0; j < VEC; ++j) {
        const int cj = c + j;
        const float wval = (cj >= c0[i]) ? __builtin_nontemporal_load(wrow[i] + cj)
                                         : 0.0f;
        const float* xe;
#pragma unroll
        for (int b = 0; b < BATCH; ++b) {
          xe = reinterpret_cast<const float*>(&xv[b]);
          acc[i][b] = fmaf(wval, xe[j], acc[i][b]);
        }
      }
    }
  }
  __syncthreads();   // vmcnt(0): buf0 DMA complete; edge compute covered the wait

  // ---- Main loop: 2-phase async pipeline ----
  int cur = 0;
  for (int cb = cbA + TILE; cb < N; cb += TILE) {
    const int c = cb + c4;
    // 1) x loads FIRST (oldest in vmcnt queue: compiler's counted wait for x
    //    does not force the newer DMA to complete).
    float4 xv[BATCH];
#pragma unroll
    for (int b = 0; b < BATCH; ++b)
      xv[b] = *(const float4*)(x + b * N + c);
    // 2) async-stage NEXT tile into the other buffer (no dest regs).
    if (cb + TILE < N) {
      const int nb = (cur ^ 1) * 4096;
#pragma unroll
      for (int k = 0; k < 16; ++k)
        stage_dword(wsrc + (cb + TILE) + k * 64 + lane,
                    &smem[nb + wv * 1024 + k * 64]);
    }
    // 3) compute current tile from LDS (ds_read_b128, contiguous: conflict-free).
#pragma unroll
    for (int i = 0; i < ROWS; ++i) {
      const f32x4 wv4 = *(const f32x4*)&smem[cur * 4096 + i * 1024 + c4];
#pragma unroll
      for (int j = 0; j < VEC; ++j) {
        const float* xe;
#pragma unroll
        for (int b = 0; b < BATCH; ++b) {
          xe = reinterpret_cast<const float*>(&xv[b]);
          acc[i][b] = fmaf(wv4[j], xe[j], acc[i][b]);
        }
      }
    }
    // 4) one barrier per tile: drains the next-tile DMA (which had the whole
    //    compute phase in flight) and fences buffer reuse.
    __syncthreads();
    cur ^= 1;
  }

  // ---- Reduction: aliased onto smem (all ds_reads fenced by loop's last barrier) ----
  float (*red)[ROWS * BATCH + 1] = reinterpret_cast<float(*)[ROWS * BATCH + 1]>(smem);
  float (*red2)[9] = reinterpret_cast<float(*)[9]>(smem + 256 * (ROWS * BATCH + 1));
#pragma unroll
  for (int i = 0; i < ROWS; ++i)
#pragma unroll
    for (int b = 0; b < BATCH; ++b)
      red[t][i * BATCH + b] = acc[i][b];
  __syncthreads();

  const int s = t & 31;     // which (row,batch) sum
  const int part = t >> 5;  // which 32-thread chunk
  float p = 0.0f;
#pragma unroll
  for (int k = 0; k < 32; ++k) p += red[part * 32 + k][s];

  red2[s][part] = p;
  __syncthreads();

  if (t < 32) {
    float total = 0.0f;
#pragma unroll
    for (int g = 0; g < 8; ++g) total += red2[t][g];
    const int i = t >> 3, b = t & 7;   // t == i*BATCH + b == s
    const int r = r0 + i;
    out[b * N + (N - 1 - r)] = total + bias[r];  // last-dim flip + bias
  }
}

extern "C" void kernel_launch(void* const* d_in, const int* in_sizes, int n_in,
                              void* d_out, int out_size, void* d_ws, size_t ws_size,
                              hipStream_t stream) {
  const float* x    = (const float*)d_in[0];  // [8, 8192]
  const float* w    = (const float*)d_in[1];  // [33591286] packed triangular
  const float* bias = (const float*)d_in[2];  // [8192]
  float* out = (float*)d_out;                 // [8, 8192]
  tri_linear_kernel<<<N / ROWS, THREADS, 0, stream>>>(x, w, bias, out);
}

// Round 11
// 201.883 us; speedup vs baseline: 1.1848x; 1.0029x over previous
//
#include <hip/hip_runtime.h>
#include <stdint.h>

// TriangleLinear: out[b][8191-r] = bias[r] + sum_{c>=max(0,r-4)} W_packed[...] * x[b][c]
// HBM floor: 134.4 MB packed-weight stream read once => ~21 us kernel.
//
// Ledger (kernel us ~= dur_us - 156 us harness fills):
//   R0/R6 register path + nt:  ~41 us (197)  | R10 DMA staging + syncthreads: ~46 (202)
//   failures: no-nt ~52 / reg-dbuf ~51-54 / shfl ~55 / VEC8 ~84 / ROWS2 ~54
// R10 diagnosis: __syncthreads()'s implicit vmcnt(0) DRAINS the just-issued
// next-tile DMA every iteration — it flies only the ~350cyc compute phase, then
// the block stalls for the remaining ~1000+cyc of HBM latency. Classic barrier-
// drain stall (guide §5/m97). absmax 0.0625 proved the DMA addressing correct.
//
// R11 = R10 skeleton + counted vmcnt + raw barriers (T4):
//   per tile: x(m) 8 loads | fence | DMA(m+1) 16 dwords | s_waitcnt vmcnt(16)
//   [retires x(m)+DMA(m) — DMA(m) flew a FULL period — keeps DMA(m+1) flying]
//   | s_barrier | sched_barrier | FMA from buf[cur] | s_barrier | flip.
// Last main tile peeled (vmcnt(16) would strand 8 of its 16 DMA writes) and
// drained with vmcnt(0). Fences pin load/DMA issue order so counts hold.
// Predict: kernel ~28-34 us => dur_us ~184-190; absmax stays 0.0625 (race check).

constexpr int N = 8192;      // N_IN == N_OUT
constexpr int BATCH = 8;
constexpr int ROWS = 4;      // rows per block
constexpr int THREADS = 256;
constexpr int VEC = 4;       // columns per thread
constexpr int TILE = THREADS * VEC;  // 1024 columns per block-iteration

typedef float f32x4 __attribute__((ext_vector_type(4)));

__device__ __forceinline__ void stage_dword(const float* gsrc, float* ldst_uniform) {
  // Async global->LDS DMA: 64 lanes x 4B. LDS dest = wave-uniform base + lane*4;
  // global src per-lane. Counts in vmcnt; no VGPR destination.
  __builtin_amdgcn_global_load_lds(
      (__attribute__((address_space(1))) void*)gsrc,
      (__attribute__((address_space(3))) void*)ldst_uniform, 4, 0, 0);
}

__global__ __launch_bounds__(THREADS, 4)
void tri_linear_kernel(const float* __restrict__ x,
                       const float* __restrict__ w,
                       const float* __restrict__ bias,
                       float* __restrict__ out) {
  const int t = threadIdx.x;
  const int r0 = blockIdx.x * ROWS;

  // smem: [0,8192) = two w tile buffers [2][ROWS][1024]; reused for reduction.
  __shared__ float smem[8736];   // 34,944 B -> 4 blocks/CU

  // Per-row triangular start column and packed-row base pointers (uniform -> SGPR).
  int c0[ROWS];
  const float* wrow[ROWS];
#pragma unroll
  for (int i = 0; i < ROWS; ++i) {
    const int r = r0 + i;
    c0[i] = (r > 4) ? (r - 4) : 0;
    // off(r) = 8192*r - (r-5)(r-4)/2 for r>=5, else 8192*r. (off(8192)=33,591,286 = nW)
    long long off = (r <= 5)
        ? (long long)r * N
        : (long long)r * N - ((long long)(r - 5) * (long long)(r - 4)) / 2;
    wrow[i] = w + (off - (long long)c0[i]);   // wrow[i][c] valid for c in [c0[i], N)
  }
  const int cbA = c0[0] & ~(TILE - 1);        // c0[0] == min c0 of this block's rows
  // c0[0] = r0-4 is a multiple of 4 => all rows' triangular starts fall inside
  // the edge tile; main-loop tiles are predicate-free and fully in-bounds.

  // This wave stages row `wv` of each tile (pointer recomputed: no dynamic
  // indexing into wrow[] -> no scratch, rule #20).
  const int wvi = t >> 6, lane = t & 63;
  const int rv = r0 + wvi;
  const int c0v = (rv > 4) ? (rv - 4) : 0;
  const long long offv = (rv <= 5)
      ? (long long)rv * N
      : (long long)rv * N - ((long long)(rv - 5) * (long long)(rv - 4)) / 2;
  const float* wsrc = w + (offv - (long long)c0v);  // wsrc[c] valid on main tiles

  float acc[ROWS][BATCH];
#pragma unroll
  for (int i = 0; i < ROWS; ++i)
#pragma unroll
    for (int b = 0; b < BATCH; ++b) acc[i][b] = 0.0f;

  const int c4 = VEC * t;   // this thread's packed column offset within a tile

  // ---- Prologue: kick off DMA of the first main tile into buf0 ----
  if (cbA + TILE < N) {
#pragma unroll
    for (int k = 0; k < 16; ++k)
      stage_dword(wsrc + (cbA + TILE) + k * 64 + lane,
                  &smem[wvi * 1024 + k * 64]);
  }

  // ---- Edge tile [cbA, cbA+TILE): predicated register path (overlaps DMA) ----
  {
    const int c = cbA + c4;
    float4 xv[BATCH];
#pragma unroll
    for (int b = 0; b < BATCH; ++b)
      xv[b] = *(const float4*)(x + b * N + c);
#pragma unroll
    for (int i = 0; i < ROWS; ++i) {
#pragma unroll
      for (int j = 0; j < VEC; ++j) {
        const int cj = c + j;
        const float wval = (cj >= c0[i]) ? __builtin_nontemporal_load(wrow[i] + cj)
                                         : 0.0f;
        const float* xe;
#pragma unroll
        for (int b = 0; b < BATCH; ++b) {
          xe = reinterpret_cast<const float*>(&xv[b]);
          acc[i][b] = fmaf(wval, xe[j], acc[i][b]);
        }
      }
    }
  }
  __syncthreads();   // full drain once: buf0 ready (edge compute covered the wait)

  // ---- Main loop (all but last tile): counted-vmcnt 2-phase pipeline ----
  int cur = 0;
  int cb = cbA + TILE;
  for (; cb + TILE < N; cb += TILE) {
    const int c = cb + c4;
    float4 xv[BATCH];
#pragma unroll
    for (int b = 0; b < BATCH; ++b)
      xv[b] = *(const float4*)(x + b * N + c);          // L2-hot, oldest in queue
    asm volatile("" ::: "memory");                      // pin: x before DMA
    {
      const int nb = (cur ^ 1) * 4096;
#pragma unroll
      for (int k = 0; k < 16; ++k)                      // DMA tile m+1 -> other buf
        stage_dword(wsrc + (cb + TILE) + k * 64 + lane,
                    &smem[nb + wvi * 1024 + k * 64]);
    }
    // Retire x(m) + DMA(m) [one full period in flight]; keep DMA(m+1) flying.
    asm volatile("s_waitcnt vmcnt(16)" ::: "memory");
    __builtin_amdgcn_s_barrier();                       // all waves' DMA(m) visible
    __builtin_amdgcn_sched_barrier(0);                  // no ds_read hoist (rule #18)
#pragma unroll
    for (int i = 0; i < ROWS; ++i) {
      const f32x4 wv4 = *(const f32x4*)&smem[cur * 4096 + i * 1024 + c4];
#pragma unroll
      for (int j = 0; j < VEC; ++j) {
        const float* xe;
#pragma unroll
        for (int b = 0; b < BATCH; ++b) {
          xe = reinterpret_cast<const float*>(&xv[b]);
          acc[i][b] = fmaf(wv4[j], xe[j], acc[i][b]);
        }
      }
    }
    __builtin_amdgcn_s_barrier();   // reads of buf[cur] done before it is re-staged
    cur ^= 1;
  }

  // ---- Peeled last main tile: full drain (vmcnt(16) would strand 8 DMA writes) ----
  if (cb < N) {
    asm volatile("s_waitcnt vmcnt(0)" ::: "memory");
    __builtin_amdgcn_s_barrier();
    __builtin_amdgcn_sched_barrier(0);
    const int c = cb + c4;
    float4 xv[BATCH];
#pragma unroll
    for (int b = 0; b < BATCH; ++b)
      xv[b] = *(const float4*)(x + b * N + c);
#pragma unroll
    for (int i = 0; i < ROWS; ++i) {
      const f32x4 wv4 = *(const f32x4*)&smem[cur * 4096 + i * 1024 + c4];
#pragma unroll
      for (int j = 0; j < VEC; ++j) {
        const float* xe;
#pragma unroll
        for (int b = 0; b < BATCH; ++b) {
          xe = reinterpret_cast<const float*>(&xv[b]);
          acc[i][b] = fmaf(wv4[j], xe[j], acc[i][b]);
        }
      }
    }
  }
  __syncthreads();   // all LDS reads done before smem is aliased by the reduction

  // ---- Reduction: aliased onto smem ----
  float (*red)[ROWS * BATCH + 1] = reinterpret_cast<float(*)[ROWS * BATCH + 1]>(smem);
  float (*red2)[9] = reinterpret_cast<float(*)[9]>(smem + 256 * (ROWS * BATCH + 1));
#pragma unroll
  for (int i = 0; i < ROWS; ++i)
#pragma unroll
    for (int b = 0; b < BATCH; ++b)
      red[t][i * BATCH + b] = acc[i][b];
  __syncthreads();

  const int s = t & 31;     // which (row,batch) sum
  const int part = t >> 5;  // which 32-thread chunk
  float p = 0.0f;
#pragma unroll
  for (int k = 0; k < 32; ++k) p += red[part * 32 + k][s];

  red2[s][part] = p;
  __syncthreads();

  if (t < 32) {
    float total = 0.0f;
#pragma unroll
    for (int g = 0; g < 8; ++g) total += red2[t][g];
    const int i = t >> 3, b = t & 7;   // t == i*BATCH + b == s
    const int r = r0 + i;
    out[b * N + (N - 1 - r)] = total + bias[r];  // last-dim flip + bias
  }
}

extern "C" void kernel_launch(void* const* d_in, const int* in_sizes, int n_in,
                              void* d_out, int out_size, void* d_ws, size_t ws_size,
                              hipStream_t stream) {
  const float* x    = (const float*)d_in[0];  // [8, 8192]
  const float* w    = (const float*)d_in[1];  // [33591286] packed triangular
  const float* bias = (const float*)d_in[2];  // [8192]
  float* out = (float*)d_out;                 // [8, 8192]
  tri_linear_kernel<<<N / ROWS, THREADS, 0, stream>>>(x, w, bias, out);
}